// Round 1
// 268.280 us; speedup vs baseline: 1.0154x; 1.0154x over previous
//
#include <hip/hip_runtime.h>
#include <math.h>

#define DM 1024
#define NH 16
#define DH 64
#define BB 4
#define SS 2048
#define MROWS (BB*SS)

typedef __bf16 bf16;
typedef __bf16 bf16x8 __attribute__((ext_vector_type(8)));
typedef float floatx4 __attribute__((ext_vector_type(4)));

#if __has_builtin(__builtin_amdgcn_exp2f)
#define EXP2F __builtin_amdgcn_exp2f
#else
#define EXP2F exp2f
#endif

#define QSCALE (0.125f * 1.44269504088896f)  // Dh^-0.5 * log2(e)

// async 16B global->LDS; lds dest = wave-uniform base + lane*16 (HW rule)
__device__ __forceinline__ void cp16(void* lds, const void* g) {
  __builtin_amdgcn_global_load_lds(
      (__attribute__((address_space(1))) void*)(void*)g,
      (__attribute__((address_space(3))) void*)lds,
      16, 0, 0);
}

// ---------------------------------------------------------------------------
// x: fp32 -> bf16
// ---------------------------------------------------------------------------
__global__ __launch_bounds__(256) void cvt_x(
    const float* __restrict__ X, bf16* __restrict__ Y) {
  int i = (blockIdx.x * 256 + threadIdx.x) * 8;
  float4 a = *(const float4*)&X[i];
  float4 b = *(const float4*)&X[i + 4];
  bf16x8 o;
  o[0] = (bf16)a.x; o[1] = (bf16)a.y; o[2] = (bf16)a.z; o[3] = (bf16)a.w;
  o[4] = (bf16)b.x; o[5] = (bf16)b.y; o[6] = (bf16)b.z; o[7] = (bf16)b.w;
  *(bf16x8*)&Y[i] = o;
}

// ---------------------------------------------------------------------------
// Weight convert+transpose: T[n][k] = (bf16)W[k][n].
// T0..T2 land contiguously (the fused QKV weight [3072][1024]); T3 = WoT.
// ---------------------------------------------------------------------------
__global__ __launch_bounds__(1024) void wtransc(
    const float* __restrict__ W0, const float* __restrict__ W1,
    const float* __restrict__ W2, const float* __restrict__ W3,
    bf16* __restrict__ T0, bf16* __restrict__ T1,
    bf16* __restrict__ T2, bf16* __restrict__ T3) {
  __shared__ float tile[32][33];
  const float* W; bf16* T;
  int z = blockIdx.z;
  if (z == 0)      { W = W0; T = T0; }
  else if (z == 1) { W = W1; T = T1; }
  else if (z == 2) { W = W2; T = T2; }
  else             { W = W3; T = T3; }
  int tx = threadIdx.x, ty = threadIdx.y;
  tile[ty][tx] = W[(blockIdx.y * 32 + ty) * DM + blockIdx.x * 32 + tx];
  __syncthreads();
  T[(blockIdx.x * 32 + ty) * DM + blockIdx.y * 32 + tx] = (bf16)tile[tx][ty];
}

// ---------------------------------------------------------------------------
// Fused QKV GEMM: [8192,1024] @ WqkvT[3072,1024]^T + bias.  128x128 tile,
// grid (24,64), 4 waves of 64x64, BK=32, global_load_lds double-buffer with
// single barrier per k-step.  Epilogue by output stream:
//   Q: (acc+b)*QSCALE -> qb          K: acc+b -> kb
//   V: acc+b -> LDS tile -> TRANSPOSED store into vt[d][s]
// ---------------------------------------------------------------------------
#define BK 32
#define TST 136  // V-transpose LDS tile stride (272 B = 17*16: b128-aligned)

__global__ __launch_bounds__(256, 3) void gemm_qkv(
    const bf16* __restrict__ A, const bf16* __restrict__ WT,
    const float* __restrict__ bq, const float* __restrict__ bk,
    const float* __restrict__ bv,
    bf16* __restrict__ qb, bf16* __restrict__ kb, bf16* __restrict__ vt) {
  __shared__ __align__(16) char smem[2 * 128 * BK * 2 * 2 > 128 * TST * 2
                                         ? 2 * 128 * BK * 2 * 2
                                         : 128 * TST * 2];
  bf16* As = (bf16*)smem;                    // [2][128*BK]
  bf16* Bs = (bf16*)smem + 2 * 128 * BK;     // [2][128*BK]
  bf16* Ts = (bf16*)smem;                    // [128][TST] (aliases, post-loop)

  int tid = threadIdx.x;
  int lane = tid & 63, w = tid >> 6;
  int wm = (w >> 1) * 64;
  int wn = (w & 1) * 64;
  int m0 = blockIdx.y * 128;
  int n0 = blockIdx.x * 128;      // global over 3072
  int which = n0 >> 10;           // 0=Q 1=K 2=V
  int qd = lane >> 4;
  int l15 = lane & 15;

  floatx4 acc[4][4] = {};

  auto stage = [&](int pb, int k0) {
    for (int i = 0; i < 2; ++i) {
      int ci = (w * 2 + i) * 64;
      int c = ci + lane;
      int r = c >> 2, cc = (c & 3) * 8;
      cp16(&As[pb * 128 * BK + ci * 8], &A[(size_t)(m0 + r) * DM + k0 + cc]);
      cp16(&Bs[pb * 128 * BK + ci * 8], &WT[(size_t)(n0 + r) * DM + k0 + cc]);
    }
  };

  stage(0, 0);
  __syncthreads();

  for (int t = 0; t < DM / BK; ++t) {
    int pb = t & 1;
    if (t + 1 < DM / BK) stage(pb ^ 1, (t + 1) * BK);
    bf16x8 af[4], bfr[4];
    for (int mt = 0; mt < 4; ++mt)
      af[mt] = *(const bf16x8*)&As[pb * 128 * BK + (wm + mt * 16 + l15) * BK + qd * 8];
    for (int nt = 0; nt < 4; ++nt)
      bfr[nt] = *(const bf16x8*)&Bs[pb * 128 * BK + (wn + nt * 16 + l15) * BK + qd * 8];
    for (int mt = 0; mt < 4; ++mt)
      for (int nt = 0; nt < 4; ++nt)
        acc[mt][nt] = __builtin_amdgcn_mfma_f32_16x16x32_bf16(
            af[mt], bfr[nt], acc[mt][nt], 0, 0, 0);
    __syncthreads();
  }

  const float* bias = (which == 0) ? bq : (which == 1) ? bk : bv;

  if (which == 2) {
    // V: bias + transpose via LDS, store vt[d][s]
    for (int nt = 0; nt < 4; ++nt) {
      int cl = wn + nt * 16 + l15;               // local col (d)
      float bv_ = bias[(n0 & 1023) + cl];
      for (int mt = 0; mt < 4; ++mt)
        for (int r = 0; r < 4; ++r)
          Ts[cl * TST + wm + mt * 16 + qd * 4 + r] = (bf16)(acc[mt][nt][r] + bv_);
    }
    __syncthreads();
    int chunk = tid & 15, colb = tid >> 4;
    for (int p = 0; p < 8; ++p) {
      int cl = p * 16 + colb;
      bf16x8 vv = *(const bf16x8*)&Ts[cl * TST + chunk * 8];
      *(bf16x8*)&vt[(size_t)((n0 & 1023) + cl) * MROWS + m0 + chunk * 8] = vv;
    }
  } else {
    bf16* out = (which == 0) ? qb : kb;
    float sc = (which == 0) ? QSCALE : 1.0f;
    for (int nt = 0; nt < 4; ++nt) {
      int col = (n0 & 1023) + wn + nt * 16 + l15;
      float bv_ = bias[col];
      for (int mt = 0; mt < 4; ++mt)
        for (int r = 0; r < 4; ++r) {
          int row = m0 + wm + mt * 16 + qd * 4 + r;
          out[(size_t)row * DM + col] = (bf16)((acc[mt][nt][r] + bv_) * sc);
        }
    }
  }
}

// ---------------------------------------------------------------------------
// Out-proj GEMM: C[M,N] = A @ WT^T + bias, fp32 out.  64x128 tile,
// grid (128, 8).  4 waves of 32x64.
// ---------------------------------------------------------------------------
__global__ __launch_bounds__(256, 4) void gemm_out(
    const bf16* __restrict__ A, const bf16* __restrict__ WT,
    const float* __restrict__ bias, float* __restrict__ C) {
  __shared__ __align__(16) bf16 As[2][64 * BK];
  __shared__ __align__(16) bf16 Bs[2][128 * BK];
  int tid = threadIdx.x;
  int lane = tid & 63, w = tid >> 6;
  int wm = (w >> 1) * 32;
  int wn = (w & 1) * 64;
  int m0 = blockIdx.x * 64;
  int n0 = blockIdx.y * 128;
  int qd = lane >> 4;
  int l15 = lane & 15;

  floatx4 acc[2][4] = {};

  auto stage = [&](int pb, int k0) {
    {  // A: 256 chunks, 1/thread
      int ci = w * 64;
      int c = ci + lane;
      int r = c >> 2, cc = (c & 3) * 8;
      cp16(&As[pb][ci * 8], &A[(size_t)(m0 + r) * DM + k0 + cc]);
    }
    for (int i = 0; i < 2; ++i) {  // B: 512 chunks, 2/thread
      int ci = (w * 2 + i) * 64;
      int c = ci + lane;
      int r = c >> 2, cc = (c & 3) * 8;
      cp16(&Bs[pb][ci * 8], &WT[(size_t)(n0 + r) * DM + k0 + cc]);
    }
  };

  stage(0, 0);
  __syncthreads();

  for (int t = 0; t < DM / BK; ++t) {
    int pb = t & 1;
    if (t + 1 < DM / BK) stage(pb ^ 1, (t + 1) * BK);
    bf16x8 af[2], bfr[4];
    for (int mt = 0; mt < 2; ++mt)
      af[mt] = *(const bf16x8*)&As[pb][(wm + mt * 16 + l15) * BK + qd * 8];
    for (int nt = 0; nt < 4; ++nt)
      bfr[nt] = *(const bf16x8*)&Bs[pb][(wn + nt * 16 + l15) * BK + qd * 8];
    for (int mt = 0; mt < 2; ++mt)
      for (int nt = 0; nt < 4; ++nt)
        acc[mt][nt] = __builtin_amdgcn_mfma_f32_16x16x32_bf16(
            af[mt], bfr[nt], acc[mt][nt], 0, 0, 0);
    __syncthreads();
  }

  for (int nt = 0; nt < 4; ++nt) {
    int col = n0 + wn + nt * 16 + l15;
    float bv = bias[col];
    for (int mt = 0; mt < 2; ++mt)
      for (int r = 0; r < 4; ++r) {
        int row = m0 + wm + mt * 16 + qd * 4 + r;
        C[(size_t)row * DM + col] = acc[mt][nt][r] + bv;
      }
  }
}

// ---------------------------------------------------------------------------
// Flash attention, causal.  PAIRED-UNIFORM grid: one block = two 128-row
// q-tiles (qt = pair and 15-pair) -> every block runs exactly 34 k-tiles;
// grid (8,16,4) = 512 blocks = exactly 2/CU, zero variance, zero tail.
// OCCUPANCY CHANGE (this round): 8 waves x 16 q-rows (512 threads) instead
// of 4 waves x 32 rows.  LDS identical (51200 B -> still 2 blocks/CU), so
// waves/CU doubles 8 -> 16 (4/EU) to hide the serial softmax/LDS chain
// (prev counters: MfmaUtil 19%, VALUBusy 38%, Occupancy 19.5% = latency-
// bound).  K-tile 64 keys; XOR-swizzled unpadded K/V staging via
// global_load_lds, single-barrier double-buffer.  Q arrives pre-scaled by
// 0.125*log2e (fused into gemm_qkv).  V pre-transposed (vt[d][s]).
// Shared max per 16-row group; l-sum via MFMA-ones; Ps wave-private.
// ---------------------------------------------------------------------------
__global__ __launch_bounds__(512, 4) void attn_fwd(
    const bf16* __restrict__ Qg, const bf16* __restrict__ Kg,
    const bf16* __restrict__ Vt, bf16* __restrict__ O) {
  __shared__ __align__(16) bf16 Kbuf[2][64 * 64];
  __shared__ __align__(16) bf16 Vbuf[2][64 * 64];
  __shared__ __align__(16) bf16 Ps[8][16][72];

  int tid = threadIdx.x;
  int lane = tid & 63, w = tid >> 6;   // w in 0..7
  int qd = lane >> 4, l15 = lane & 15;
  int sw = l15 & 7;
  int pair = blockIdx.x, h = blockIdx.y, b = blockIdx.z;
  int base = b * SS;
  int hoff = h * DH;

  int gch = ((lane & 7) ^ (lane >> 3)) * 8;
  auto stage = [&](int pb, int kt) {
    int kbase = base + kt * 64;
    int ci = w * 64;                    // 8 waves x 64 chunks = 512 chunks
    int row = (ci + lane) >> 3;
    cp16(&Kbuf[pb][ci * 8], &Kg[(size_t)(kbase + row) * DM + hoff + gch]);
    cp16(&Vbuf[pb][ci * 8],
         &Vt[(size_t)(hoff + row) * MROWS + base + kt * 64 + gch]);
  };

  bf16x8 onesf;
  for (int j = 0; j < 8; ++j) onesf[j] = (bf16)1.0f;

  for (int ph = 0; ph < 2; ++ph) {
    int qt = ph ? (15 - pair) : pair;
    int q0 = qt * 128;
    int nkt = 2 * qt + 2;

    stage(0, 0);  // safe: previous phase's last kt-barrier covers buffer 0

    bf16x8 qf[2];
    {
      int qrow = base + q0 + w * 16 + l15;
      for (int ks = 0; ks < 2; ++ks)
        qf[ks] = *(const bf16x8*)&Qg[(size_t)qrow * DM + hoff + ks * 32 + qd * 8];
    }

    float m_r = -3e38f;
    floatx4 lacc = {};
    floatx4 oacc[4] = {};

    __syncthreads();  // drains tile-0 loads (vmcnt(0) before s_barrier)

    for (int kt = 0; kt < nkt; ++kt) {
      int pb = kt & 1;
      if (kt + 1 < nkt) stage(pb ^ 1, kt + 1);

      floatx4 s[4] = {};
      for (int ks = 0; ks < 2; ++ks)
        for (int nt = 0; nt < 4; ++nt) {
          bf16x8 kf = *(const bf16x8*)
              &Kbuf[pb][(nt * 16 + l15) * 64 + (((ks << 2) + qd) ^ sw) * 8];
          s[nt] = __builtin_amdgcn_mfma_f32_16x16x32_bf16(
              qf[ks], kf, s[nt], 0, 0, 0);
        }

      if (kt >= 2 * qt) {  // diagonal tiles: causal mask
        for (int nt = 0; nt < 4; ++nt) {
          int col = kt * 64 + nt * 16 + l15;
          for (int r = 0; r < 4; ++r) {
            int row = q0 + w * 16 + qd * 4 + r;
            if (col > row) s[nt][r] = -3e38f;
          }
        }
      }

      {
        float t = s[0][0];
        for (int nt = 0; nt < 4; ++nt)
          for (int r = 0; r < 4; ++r) t = fmaxf(t, s[nt][r]);
        t = fmaxf(t, __shfl_xor(t, 1, 64));
        t = fmaxf(t, __shfl_xor(t, 2, 64));
        t = fmaxf(t, __shfl_xor(t, 4, 64));
        t = fmaxf(t, __shfl_xor(t, 8, 64));
        float mn = fmaxf(m_r, t);
        float al = EXP2F(m_r - mn);
        m_r = mn;
        for (int dt = 0; dt < 4; ++dt)
          for (int r = 0; r < 4; ++r) oacc[dt][r] *= al;
        for (int r = 0; r < 4; ++r) lacc[r] *= al;
        for (int nt = 0; nt < 4; ++nt)
          for (int r = 0; r < 4; ++r) {
            float p = EXP2F(s[nt][r] - mn);
            Ps[w][qd * 4 + r][nt * 16 + l15] = (bf16)p;
          }
      }

      bf16x8 pf[2];
      for (int ks = 0; ks < 2; ++ks)
        pf[ks] = *(const bf16x8*)&Ps[w][l15][ks * 32 + qd * 8];

      for (int ks = 0; ks < 2; ++ks)
        for (int dt = 0; dt < 4; ++dt) {
          bf16x8 vf = *(const bf16x8*)
              &Vbuf[pb][(dt * 16 + l15) * 64 + (((ks << 2) + qd) ^ sw) * 8];
          oacc[dt] = __builtin_amdgcn_mfma_f32_16x16x32_bf16(
              pf[ks], vf, oacc[dt], 0, 0, 0);
        }
      for (int ks = 0; ks < 2; ++ks)
        lacc = __builtin_amdgcn_mfma_f32_16x16x32_bf16(
            pf[ks], onesf, lacc, 0, 0, 0);

      __syncthreads();  // single barrier/tile: drains async loads post-compute
    }

    for (int r = 0; r < 4; ++r) {
      float inv = 1.0f / lacc[r];
      int row = base + q0 + w * 16 + qd * 4 + r;
      for (int dt = 0; dt < 4; ++dt)
        O[(size_t)row * DM + hoff + dt * 16 + l15] = (bf16)(oacc[dt][r] * inv);
    }
  }
}

// ---------------------------------------------------------------------------
extern "C" void kernel_launch(void* const* d_in, const int* in_sizes, int n_in,
                              void* d_out, int out_size, void* d_ws, size_t ws_size,
                              hipStream_t stream) {
  const float* x  = (const float*)d_in[0];
  const float* Wq = (const float*)d_in[1];
  const float* bq = (const float*)d_in[2];
  const float* Wk = (const float*)d_in[3];
  const float* bk = (const float*)d_in[4];
  const float* Wv = (const float*)d_in[5];
  const float* bv = (const float*)d_in[6];
  const float* Wo = (const float*)d_in[7];
  const float* bo = (const float*)d_in[8];
  float* out = (float*)d_out;

  char* ws = (char*)d_ws;
  const size_t act = (size_t)MROWS * DM * sizeof(bf16);  // 16.8 MB
  bf16* xb    = (bf16*)(ws);
  bf16* qb    = (bf16*)(ws + act);
  bf16* kb    = (bf16*)(ws + 2 * act);
  bf16* vt    = (bf16*)(ws + 3 * act);   // [1024][8192]
  bf16* ab    = (bf16*)(ws + 4 * act);
  bf16* WqkvT = (bf16*)(ws + 5 * act);   // [3072][1024]
  bf16* WoT   = WqkvT + 3 * (size_t)DM * DM;

  cvt_x<<<MROWS * DM / (256 * 8), 256, 0, stream>>>(x, xb);
  wtransc<<<dim3(32, 32, 4), dim3(32, 32), 0, stream>>>(
      Wq, Wk, Wv, Wo,
      WqkvT, WqkvT + (size_t)DM * DM, WqkvT + 2 * (size_t)DM * DM, WoT);

  gemm_qkv<<<dim3(24, 64), 256, 0, stream>>>(
      xb, WqkvT, bq, bk, bv, qb, kb, vt);

  attn_fwd<<<dim3(8, NH, BB), 512, 0, stream>>>(qb, kb, vt, ab);

  gemm_out<<<dim3(128, 8), 256, 0, stream>>>(ab, WoT, bo, out);
}

// Round 3
// 258.671 us; speedup vs baseline: 1.0532x; 1.0371x over previous
//
#include <hip/hip_runtime.h>
#include <math.h>

#define DM 1024
#define NH 16
#define DH 64
#define BB 4
#define SS 2048
#define MROWS (BB*SS)

typedef __bf16 bf16;
typedef __bf16 bf16x2 __attribute__((ext_vector_type(2)));
typedef __bf16 bf16x8 __attribute__((ext_vector_type(8)));
typedef float floatx4 __attribute__((ext_vector_type(4)));
typedef unsigned int uintx4 __attribute__((ext_vector_type(4)));
typedef unsigned int uintx2 __attribute__((ext_vector_type(2)));

#if __has_builtin(__builtin_amdgcn_exp2f)
#define EXP2F __builtin_amdgcn_exp2f
#else
#define EXP2F exp2f
#endif

#define QSCALE (0.125f * 1.44269504088896f)  // Dh^-0.5 * log2(e)

// async 16B global->LDS; lds dest = wave-uniform base + lane*16 (HW rule)
__device__ __forceinline__ void cp16(void* lds, const void* g) {
  __builtin_amdgcn_global_load_lds(
      (__attribute__((address_space(1))) void*)(void*)g,
      (__attribute__((address_space(3))) void*)lds,
      16, 0, 0);
}

// pack two f32 -> packed bf16x2 word (compiler emits cvt_pk)
__device__ __forceinline__ unsigned pk2(float a, float b) {
  bf16x2 t;
  t[0] = (bf16)a;
  t[1] = (bf16)b;
  return __builtin_bit_cast(unsigned, t);
}

// lane-half swaps (gfx950).  After pl32: a=[A0-31|B0-31], b=[A32-63|B32-63].
#if __has_builtin(__builtin_amdgcn_permlane32_swap) && \
    __has_builtin(__builtin_amdgcn_permlane16_swap)
__device__ __forceinline__ void pl32(unsigned& a, unsigned& b) {
  uintx2 r = __builtin_amdgcn_permlane32_swap(a, b, false, false);
  a = r[0]; b = r[1];
}
__device__ __forceinline__ void pl16(unsigned& a, unsigned& b) {
  uintx2 r = __builtin_amdgcn_permlane16_swap(a, b, false, false);
  a = r[0]; b = r[1];
}
#else
__device__ __forceinline__ void pl32(unsigned& a, unsigned& b) {
  asm volatile("v_permlane32_swap_b32 %0, %1" : "+v"(a), "+v"(b));
}
__device__ __forceinline__ void pl16(unsigned& a, unsigned& b) {
  asm volatile("v_permlane16_swap_b32 %0, %1" : "+v"(a), "+v"(b));
}
#endif

// ---------------------------------------------------------------------------
// x: fp32 -> bf16
// ---------------------------------------------------------------------------
__global__ __launch_bounds__(256) void cvt_x(
    const float* __restrict__ X, bf16* __restrict__ Y) {
  int i = (blockIdx.x * 256 + threadIdx.x) * 8;
  float4 a = *(const float4*)&X[i];
  float4 b = *(const float4*)&X[i + 4];
  bf16x8 o;
  o[0] = (bf16)a.x; o[1] = (bf16)a.y; o[2] = (bf16)a.z; o[3] = (bf16)a.w;
  o[4] = (bf16)b.x; o[5] = (bf16)b.y; o[6] = (bf16)b.z; o[7] = (bf16)b.w;
  *(bf16x8*)&Y[i] = o;
}

// ---------------------------------------------------------------------------
// Weight convert+transpose: T[n][k] = (bf16)W[k][n].
// T0..T2 land contiguously (the fused QKV weight [3072][1024]); T3 = WoT.
// ---------------------------------------------------------------------------
__global__ __launch_bounds__(1024) void wtransc(
    const float* __restrict__ W0, const float* __restrict__ W1,
    const float* __restrict__ W2, const float* __restrict__ W3,
    bf16* __restrict__ T0, bf16* __restrict__ T1,
    bf16* __restrict__ T2, bf16* __restrict__ T3) {
  __shared__ float tile[32][33];
  const float* W; bf16* T;
  int z = blockIdx.z;
  if (z == 0)      { W = W0; T = T0; }
  else if (z == 1) { W = W1; T = T1; }
  else if (z == 2) { W = W2; T = T2; }
  else             { W = W3; T = T3; }
  int tx = threadIdx.x, ty = threadIdx.y;
  tile[ty][tx] = W[(blockIdx.y * 32 + ty) * DM + blockIdx.x * 32 + tx];
  __syncthreads();
  T[(blockIdx.x * 32 + ty) * DM + blockIdx.y * 32 + tx] = (bf16)tile[tx][ty];
}

// ---------------------------------------------------------------------------
// Fused QKV GEMM: [8192,1024] @ WqkvT[3072,1024]^T + bias.  128x128 tile,
// grid (24,64), 4 waves of 64x64, BK=32, global_load_lds double-buffer with
// single barrier per k-step.  Epilogue by output stream:
//   Q: (acc+b)*QSCALE -> qb          K: acc+b -> kb
//   V: acc+b -> LDS tile -> TRANSPOSED store into vt[d][s]
// ---------------------------------------------------------------------------
#define BK 32
#define TST 136  // V-transpose LDS tile stride (272 B = 17*16: b128-aligned)

__global__ __launch_bounds__(256, 3) void gemm_qkv(
    const bf16* __restrict__ A, const bf16* __restrict__ WT,
    const float* __restrict__ bq, const float* __restrict__ bk,
    const float* __restrict__ bv,
    bf16* __restrict__ qb, bf16* __restrict__ kb, bf16* __restrict__ vt) {
  __shared__ __align__(16) char smem[2 * 128 * BK * 2 * 2 > 128 * TST * 2
                                         ? 2 * 128 * BK * 2 * 2
                                         : 128 * TST * 2];
  bf16* As = (bf16*)smem;                    // [2][128*BK]
  bf16* Bs = (bf16*)smem + 2 * 128 * BK;     // [2][128*BK]
  bf16* Ts = (bf16*)smem;                    // [128][TST] (aliases, post-loop)

  int tid = threadIdx.x;
  int lane = tid & 63, w = tid >> 6;
  int wm = (w >> 1) * 64;
  int wn = (w & 1) * 64;
  int m0 = blockIdx.y * 128;
  int n0 = blockIdx.x * 128;      // global over 3072
  int which = n0 >> 10;           // 0=Q 1=K 2=V
  int qd = lane >> 4;
  int l15 = lane & 15;

  floatx4 acc[4][4] = {};

  auto stage = [&](int pb, int k0) {
    for (int i = 0; i < 2; ++i) {
      int ci = (w * 2 + i) * 64;
      int c = ci + lane;
      int r = c >> 2, cc = (c & 3) * 8;
      cp16(&As[pb * 128 * BK + ci * 8], &A[(size_t)(m0 + r) * DM + k0 + cc]);
      cp16(&Bs[pb * 128 * BK + ci * 8], &WT[(size_t)(n0 + r) * DM + k0 + cc]);
    }
  };

  stage(0, 0);
  __syncthreads();

  for (int t = 0; t < DM / BK; ++t) {
    int pb = t & 1;
    if (t + 1 < DM / BK) stage(pb ^ 1, (t + 1) * BK);
    bf16x8 af[4], bfr[4];
    for (int mt = 0; mt < 4; ++mt)
      af[mt] = *(const bf16x8*)&As[pb * 128 * BK + (wm + mt * 16 + l15) * BK + qd * 8];
    for (int nt = 0; nt < 4; ++nt)
      bfr[nt] = *(const bf16x8*)&Bs[pb * 128 * BK + (wn + nt * 16 + l15) * BK + qd * 8];
    for (int mt = 0; mt < 4; ++mt)
      for (int nt = 0; nt < 4; ++nt)
        acc[mt][nt] = __builtin_amdgcn_mfma_f32_16x16x32_bf16(
            af[mt], bfr[nt], acc[mt][nt], 0, 0, 0);
    __syncthreads();
  }

  const float* bias = (which == 0) ? bq : (which == 1) ? bk : bv;

  if (which == 2) {
    // V: bias + transpose via LDS, store vt[d][s]
    for (int nt = 0; nt < 4; ++nt) {
      int cl = wn + nt * 16 + l15;               // local col (d)
      float bv_ = bias[(n0 & 1023) + cl];
      for (int mt = 0; mt < 4; ++mt)
        for (int r = 0; r < 4; ++r)
          Ts[cl * TST + wm + mt * 16 + qd * 4 + r] = (bf16)(acc[mt][nt][r] + bv_);
    }
    __syncthreads();
    int chunk = tid & 15, colb = tid >> 4;
    for (int p = 0; p < 8; ++p) {
      int cl = p * 16 + colb;
      bf16x8 vv = *(const bf16x8*)&Ts[cl * TST + chunk * 8];
      *(bf16x8*)&vt[(size_t)((n0 & 1023) + cl) * MROWS + m0 + chunk * 8] = vv;
    }
  } else {
    bf16* out = (which == 0) ? qb : kb;
    float sc = (which == 0) ? QSCALE : 1.0f;
    for (int nt = 0; nt < 4; ++nt) {
      int col = (n0 & 1023) + wn + nt * 16 + l15;
      float bv_ = bias[col];
      for (int mt = 0; mt < 4; ++mt)
        for (int r = 0; r < 4; ++r) {
          int row = m0 + wm + mt * 16 + qd * 4 + r;
          out[(size_t)row * DM + col] = (bf16)((acc[mt][nt][r] + bv_) * sc);
        }
    }
  }
}

// ---------------------------------------------------------------------------
// Out-proj GEMM: C[M,N] = A @ WT^T + bias, fp32 out.  64x128 tile,
// grid (128, 8).  4 waves of 32x64.
// ---------------------------------------------------------------------------
__global__ __launch_bounds__(256, 4) void gemm_out(
    const bf16* __restrict__ A, const bf16* __restrict__ WT,
    const float* __restrict__ bias, float* __restrict__ C) {
  __shared__ __align__(16) bf16 As[2][64 * BK];
  __shared__ __align__(16) bf16 Bs[2][128 * BK];
  int tid = threadIdx.x;
  int lane = tid & 63, w = tid >> 6;
  int wm = (w >> 1) * 32;
  int wn = (w & 1) * 64;
  int m0 = blockIdx.x * 64;
  int n0 = blockIdx.y * 128;
  int qd = lane >> 4;
  int l15 = lane & 15;

  floatx4 acc[2][4] = {};

  auto stage = [&](int pb, int k0) {
    {  // A: 256 chunks, 1/thread
      int ci = w * 64;
      int c = ci + lane;
      int r = c >> 2, cc = (c & 3) * 8;
      cp16(&As[pb][ci * 8], &A[(size_t)(m0 + r) * DM + k0 + cc]);
    }
    for (int i = 0; i < 2; ++i) {  // B: 512 chunks, 2/thread
      int ci = (w * 2 + i) * 64;
      int c = ci + lane;
      int r = c >> 2, cc = (c & 3) * 8;
      cp16(&Bs[pb][ci * 8], &WT[(size_t)(n0 + r) * DM + k0 + cc]);
    }
  };

  stage(0, 0);
  __syncthreads();

  for (int t = 0; t < DM / BK; ++t) {
    int pb = t & 1;
    if (t + 1 < DM / BK) stage(pb ^ 1, (t + 1) * BK);
    bf16x8 af[2], bfr[4];
    for (int mt = 0; mt < 2; ++mt)
      af[mt] = *(const bf16x8*)&As[pb][(wm + mt * 16 + l15) * BK + qd * 8];
    for (int nt = 0; nt < 4; ++nt)
      bfr[nt] = *(const bf16x8*)&Bs[pb][(wn + nt * 16 + l15) * BK + qd * 8];
    for (int mt = 0; mt < 2; ++mt)
      for (int nt = 0; nt < 4; ++nt)
        acc[mt][nt] = __builtin_amdgcn_mfma_f32_16x16x32_bf16(
            af[mt], bfr[nt], acc[mt][nt], 0, 0, 0);
    __syncthreads();
  }

  for (int nt = 0; nt < 4; ++nt) {
    int col = n0 + wn + nt * 16 + l15;
    float bv = bias[col];
    for (int mt = 0; mt < 2; ++mt)
      for (int r = 0; r < 4; ++r) {
        int row = m0 + wm + mt * 16 + qd * 4 + r;
        C[(size_t)row * DM + col] = acc[mt][nt][r] + bv;
      }
  }
}

// ---------------------------------------------------------------------------
// Flash attention, causal.  PAIRED-UNIFORM grid: one block = two 128-row
// q-tiles -> every block runs exactly 34 k-tiles; grid (8,16,4) = 512 blocks
// = exactly 2/CU.  8 waves x 16 q-rows, 512 threads.
//
// T12: swapped QK^T -> in-register softmax, NO P LDS round-trip.
//   mfma(kf, qf) gives S^T: lane holds q = l15, keys = nt*16 + qd*4 + r.
//   (A-frag and B-frag share per-lane addressing, so ALL LDS reads are
//   unchanged -- only the mfma argument order swaps.)
//   Row-max: in-lane 16 + shfl_xor(16,32).  l-sum: in-lane f32 adds,
//   cross-qd reduced ONCE per phase.  P -> PV A-frag (q=l15, keys qd*8+j)
//   via pk2 + permlane32_swap + permlane16_swap (builtins; 8 packs + 8
//   swaps per tile replace 16 ds_write_b16 + 2 ds_read_b128 + lgkm wait).
//   Derivation: pl32 makes u=[U0-31|V0-31]; pl16 then yields
//   u=[U0-15,U32-47,V0-15,V32-47] = word0 lanes, v = word2 lanes.
//   PV unchanged: mfma(pf, vf); output rows q = qd*4+r; norm via shfl.
//   T13 defer-max: skip O-rescale unless tile max exceeds m by >11 (log2).
//   Ps buffer deleted: LDS 51200 -> 32768 B.
// ---------------------------------------------------------------------------
__global__ __launch_bounds__(512, 4) void attn_fwd(
    const bf16* __restrict__ Qg, const bf16* __restrict__ Kg,
    const bf16* __restrict__ Vt, bf16* __restrict__ O) {
  __shared__ __align__(16) bf16 Kbuf[2][64 * 64];
  __shared__ __align__(16) bf16 Vbuf[2][64 * 64];

  int tid = threadIdx.x;
  int lane = tid & 63, w = tid >> 6;   // w in 0..7
  int qd = lane >> 4, l15 = lane & 15;
  int sw = l15 & 7;
  int pair = blockIdx.x, h = blockIdx.y, b = blockIdx.z;
  int base = b * SS;
  int hoff = h * DH;

  int gch = ((lane & 7) ^ (lane >> 3)) * 8;
  auto stage = [&](int pb, int kt) {
    int kbase = base + kt * 64;
    int ci = w * 64;                    // 8 waves x 64 chunks = 512 chunks
    int row = (ci + lane) >> 3;
    cp16(&Kbuf[pb][ci * 8], &Kg[(size_t)(kbase + row) * DM + hoff + gch]);
    cp16(&Vbuf[pb][ci * 8],
         &Vt[(size_t)(hoff + row) * MROWS + base + kt * 64 + gch]);
  };

  for (int ph = 0; ph < 2; ++ph) {
    int qt = ph ? (15 - pair) : pair;
    int q0 = qt * 128;
    int nkt = 2 * qt + 2;

    stage(0, 0);  // safe: previous phase's last kt-barrier covers buffer 0

    bf16x8 qf[2];
    {
      int qrow = base + q0 + w * 16 + l15;
      for (int ks = 0; ks < 2; ++ks)
        qf[ks] = *(const bf16x8*)&Qg[(size_t)qrow * DM + hoff + ks * 32 + qd * 8];
    }

    float m_r = -3e38f;
    float lacc = 0.0f;
    floatx4 oacc[4] = {};

    __syncthreads();  // drains tile-0 loads (vmcnt(0) before s_barrier)

    for (int kt = 0; kt < nkt; ++kt) {
      int pb = kt & 1;
      if (kt + 1 < nkt) stage(pb ^ 1, kt + 1);

      // S^T = K . Q^T : lane holds q = l15, key = kt*64 + nt*16 + qd*4 + r
      floatx4 s[4] = {};
      for (int ks = 0; ks < 2; ++ks)
        for (int nt = 0; nt < 4; ++nt) {
          bf16x8 kf = *(const bf16x8*)
              &Kbuf[pb][(nt * 16 + l15) * 64 + (((ks << 2) + qd) ^ sw) * 8];
          s[nt] = __builtin_amdgcn_mfma_f32_16x16x32_bf16(
              kf, qf[ks], s[nt], 0, 0, 0);
        }

      int rowq = q0 + w * 16 + l15;
      if (kt >= 2 * qt) {  // diagonal tiles: causal mask
        for (int nt = 0; nt < 4; ++nt)
          for (int r = 0; r < 4; ++r) {
            int col = kt * 64 + nt * 16 + qd * 4 + r;
            if (col > rowq) s[nt][r] = -3e38f;
          }
      }

      // per-row max over this tile's 64 keys
      floatx4 m4 = s[0];
      for (int nt = 1; nt < 4; ++nt)
        for (int r = 0; r < 4; ++r) m4[r] = fmaxf(m4[r], s[nt][r]);
      float t = fmaxf(fmaxf(m4[0], m4[1]), fmaxf(m4[2], m4[3]));
      t = fmaxf(t, __shfl_xor(t, 16, 64));
      t = fmaxf(t, __shfl_xor(t, 32, 64));

      // T13 defer-max: only rescale when max grows by > 11 (log2 units)
      if (!__all(t <= m_r + 11.0f)) {
        float mn = fmaxf(m_r, t);
        float al = EXP2F(m_r - mn);
        m_r = mn;
        for (int dt = 0; dt < 4; ++dt)
          for (int r = 0; r < 4; ++r) oacc[dt][r] *= al;
        lacc *= al;
      }

      // exp, in-lane sum, pack + permlane rearrange -> PV A-frags
      bf16x8 pf[2];
      for (int ks = 0; ks < 2; ++ks) {
        float pu[4], pv[4];
        for (int r = 0; r < 4; ++r) {
          pu[r] = EXP2F(s[2 * ks][r] - m_r);
          pv[r] = EXP2F(s[2 * ks + 1][r] - m_r);
        }
        lacc += ((pu[0] + pu[1]) + (pu[2] + pu[3])) +
                ((pv[0] + pv[1]) + (pv[2] + pv[3]));
        unsigned u0 = pk2(pu[0], pu[1]), u1 = pk2(pu[2], pu[3]);
        unsigned v0 = pk2(pv[0], pv[1]), v1 = pk2(pv[2], pv[3]);
        pl32(u0, v0); pl16(u0, v0);   // u0 -> word0 lanes, v0 -> word2
        pl32(u1, v1); pl16(u1, v1);   // u1 -> word1 lanes, v1 -> word3
        uintx4 ww;
        ww[0] = u0; ww[1] = u1; ww[2] = v0; ww[3] = v1;
        pf[ks] = __builtin_bit_cast(bf16x8, ww);
      }

      for (int ks = 0; ks < 2; ++ks)
        for (int dt = 0; dt < 4; ++dt) {
          bf16x8 vf = *(const bf16x8*)
              &Vbuf[pb][(dt * 16 + l15) * 64 + (((ks << 2) + qd) ^ sw) * 8];
          oacc[dt] = __builtin_amdgcn_mfma_f32_16x16x32_bf16(
              pf[ks], vf, oacc[dt], 0, 0, 0);
        }

      __syncthreads();  // single barrier/tile: drains async loads post-compute
    }

    // cross-qd l reduction (once per phase), then normalize + store.
    lacc += __shfl_xor(lacc, 16, 64);
    lacc += __shfl_xor(lacc, 32, 64);
    for (int r = 0; r < 4; ++r) {
      float inv = 1.0f / __shfl(lacc, qd * 4 + r, 64);
      int row = base + q0 + w * 16 + qd * 4 + r;
      for (int dt = 0; dt < 4; ++dt)
        O[(size_t)row * DM + hoff + dt * 16 + l15] = (bf16)(oacc[dt][r] * inv);
    }
  }
}

// ---------------------------------------------------------------------------
extern "C" void kernel_launch(void* const* d_in, const int* in_sizes, int n_in,
                              void* d_out, int out_size, void* d_ws, size_t ws_size,
                              hipStream_t stream) {
  const float* x  = (const float*)d_in[0];
  const float* Wq = (const float*)d_in[1];
  const float* bq = (const float*)d_in[2];
  const float* Wk = (const float*)d_in[3];
  const float* bk = (const float*)d_in[4];
  const float* Wv = (const float*)d_in[5];
  const float* bv = (const float*)d_in[6];
  const float* Wo = (const float*)d_in[7];
  const float* bo = (const float*)d_in[8];
  float* out = (float*)d_out;

  char* ws = (char*)d_ws;
  const size_t act = (size_t)MROWS * DM * sizeof(bf16);  // 16.8 MB
  bf16* xb    = (bf16*)(ws);
  bf16* qb    = (bf16*)(ws + act);
  bf16* kb    = (bf16*)(ws + 2 * act);
  bf16* vt    = (bf16*)(ws + 3 * act);   // [1024][8192]
  bf16* ab    = (bf16*)(ws + 4 * act);
  bf16* WqkvT = (bf16*)(ws + 5 * act);   // [3072][1024]
  bf16* WoT   = WqkvT + 3 * (size_t)DM * DM;

  cvt_x<<<MROWS * DM / (256 * 8), 256, 0, stream>>>(x, xb);
  wtransc<<<dim3(32, 32, 4), dim3(32, 32), 0, stream>>>(
      Wq, Wk, Wv, Wo,
      WqkvT, WqkvT + (size_t)DM * DM, WqkvT + 2 * (size_t)DM * DM, WoT);

  gemm_qkv<<<dim3(24, 64), 256, 0, stream>>>(
      xb, WqkvT, bq, bk, bv, qb, kb, vt);

  attn_fwd<<<dim3(8, NH, BB), 512, 0, stream>>>(qb, kb, vt, ab);

  gemm_out<<<dim3(128, 8), 256, 0, stream>>>(ab, WoT, bo, out);
}